// Round 5
// baseline (9019.398 us; speedup 1.0000x reference)
//
#include <hip/hip_runtime.h>
#include <math.h>

#define BATCH 128
#define TSTEPS 4096
#define INDIM 13

// ============================================================================
// R5: wave-specialized, barrier-free steady loop.
//  W0 (critical wave): per step ts:
//   S1 LSTM: P(ts) [helpers: bias+x+o0+o1 parts] + o2-part (6 cols) -> c,h
//   S2 CfC0: h0-dot (lanes<35 real)   + partial[x+bias]   -> o0
//   S3 CfC1: o0-dot (lanes 35-57)     + partial[h1+bias]  -> o1
//   S4 CfC2: o1-dot (lanes 58-63)     + partial[h2+bias]  -> o2
//   Homogeneous 36-col dot per stage (wcA = per-lane-role weights).
//  W1: LSTM partials u0-15 | CfC1 h1-partials.  W2: LSTM u16-31 | CfC0
//  x-partials | CfC2 h2-partials | out-tile copy+flush.  W3: LSTM u32-63 |
//  x-tile refill.  Handoff: LDS flags (lgkmcnt(0) release + volatile poll).
//
// LDS (floats): flags@0(16) PS1@16 PS2@528 PS3@1040 PS4@1552 [2][256] each
//  HB@2064[2][64] O0B@2192[2][36] O1B@2264[2][36] O2B@2336[2][8]
//  XT0@2352 XT1@3184 (832) OT0@4016 OT1@4400 (384)
// ============================================================================

#define FLG_PS1 16
#define FLG_PS2 528
#define FLG_PS3 1040
#define FLG_PS4 1552
#define OFF_HB  2064
#define OFF_O0  2192
#define OFF_O1  2264
#define OFF_O2  2336
#define OFF_XT0 2352
#define OFF_XT1 3184
#define OFF_OT0 4016
#define OFF_OT1 4400
#define STOT    4784

#define F_P0 0
#define F_P1 1
#define F_P2 2
#define F_H  3
#define F_O0 4
#define F_O1 5
#define F_O2 6
#define F_A1 7
#define F_A2 8

__device__ __forceinline__ float fsig(float x) {
    return __builtin_amdgcn_rcpf(1.f + __expf(-x));
}
__device__ __forceinline__ float ftanh(float x) {
    float s = fsig(x + x);
    return s + s - 1.f;
}
__device__ __forceinline__ float fsoftplus(float x) {
    return (x > 15.f) ? x : __logf(1.f + __expf(x));
}

// producer release: drain LDS writes, then lane 0 publishes flag
#define FENCE() { asm volatile("s_waitcnt lgkmcnt(0)" ::: "memory"); \
                  __builtin_amdgcn_sched_barrier(0); }
#define PUBLISH(F, V) { FENCE(); if (l == 0) flg[F] = (V); }
// consumer acquire: spin until flag >= V
#define POLL(F, V) { while (flg[F] < (V)) {} __builtin_amdgcn_sched_barrier(0); }

// homogeneous 36-col x 4-gate dot + CfC nonlinearity (W0 stages 2-4)
#define STAGE36(OUT, OPOFF, POFF) float OUT; { \
    const float4* _q = (const float4*)(smem + (OPOFF)); \
    float4 _v0=_q[0],_v1=_q[1],_v2=_q[2],_v3=_q[3],_v4=_q[4], \
           _v5=_q[5],_v6=_q[6],_v7=_q[7],_v8=_q[8]; \
    float4 _P = *(const float4*)(smem + (POFF) + 4*l); \
    float _op[36] = {_v0.x,_v0.y,_v0.z,_v0.w,_v1.x,_v1.y,_v1.z,_v1.w, \
                     _v2.x,_v2.y,_v2.z,_v2.w,_v3.x,_v3.y,_v3.z,_v3.w, \
                     _v4.x,_v4.y,_v4.z,_v4.w,_v5.x,_v5.y,_v5.z,_v5.w, \
                     _v6.x,_v6.y,_v6.z,_v6.w,_v7.x,_v7.y,_v7.z,_v7.w, \
                     _v8.x,_v8.y,_v8.z,_v8.w}; \
    float _a0=_P.x,_a1=_P.y,_a2=_P.z,_a3=_P.w; \
    _Pragma("unroll") \
    for (int _j = 0; _j < 36; ++_j) { \
        _a0 += _op[_j]*wcA[0][_j]; _a1 += _op[_j]*wcA[1][_j]; \
        _a2 += _op[_j]*wcA[2][_j]; _a3 += _op[_j]*wcA[3][_j]; } \
    float _tg = fsig(_a2+_a3), _f1 = ftanh(_a0), _f2 = ftanh(_a1); \
    OUT = _f1 + _tg*(_f2-_f1); }

__global__ __launch_bounds__(256, 1)
void rnn_kernel(const float* __restrict__ x,
                const float* __restrict__ lstm_wi, const float* __restrict__ lstm_wh,
                const float* __restrict__ lstm_b,
                const float* __restrict__ c0w1, const float* __restrict__ c0w2,
                const float* __restrict__ c0wa, const float* __restrict__ c0wb,
                const float* __restrict__ c0b1, const float* __restrict__ c0b2,
                const float* __restrict__ c0ba, const float* __restrict__ c0bb,
                const float* __restrict__ c1w1, const float* __restrict__ c1w2,
                const float* __restrict__ c1wa, const float* __restrict__ c1wb,
                const float* __restrict__ c1b1, const float* __restrict__ c1b2,
                const float* __restrict__ c1ba, const float* __restrict__ c1bb,
                const float* __restrict__ c2w1, const float* __restrict__ c2w2,
                const float* __restrict__ c2wa, const float* __restrict__ c2wb,
                const float* __restrict__ c2b1, const float* __restrict__ c2b2,
                const float* __restrict__ c2ba, const float* __restrict__ c2bb,
                float* __restrict__ out)
{
    const int t = threadIdx.x;
    const int l = t & 63;
    const int w = t >> 6;

    __shared__ __align__(16) float smem[STOT];
    volatile int* flg = (volatile int*)smem;

    const long xbase = (long)blockIdx.x * TSTEPS * INDIM;
    const long obase = (long)blockIdx.x * TSTEPS * 6;

    // ---- prologue: zero state/partials/flags, load x tile 0 ----
    for (int i = t; i < OFF_XT0; i += 256) smem[i] = 0.f;
    if (t < 208) {
        float4 xi = *(const float4*)(x + xbase + 4 * t);
        *(float4*)&smem[OFF_XT0 + 4 * t] = xi;
    }
    __syncthreads();
    if (t == 0) {
        #pragma unroll
        for (int i = 0; i < 9; ++i) flg[i] = -1;
    }
    __syncthreads();

    if (w == 0) {
        // ================= W0: critical wave =================
        // S1 weights: o2 columns (h[58..64)) of all 4 gates for unit l
        float wlA[4][6];
        #pragma unroll
        for (int g = 0; g < 4; ++g)
            #pragma unroll
            for (int j = 0; j < 6; ++j)
                wlA[g][j] = lstm_wh[((g << 6) + l) * 64 + 58 + j];
        // role weights: lanes<35 CfC0(h0) | 35-57 CfC1(o0) | 58-63 CfC2(o1)
        float wcA[4][36];
        #pragma unroll
        for (int g = 0; g < 4; ++g)
            #pragma unroll
            for (int j = 0; j < 36; ++j) wcA[g][j] = 0.f;
        if (l < 35) {
            #pragma unroll
            for (int g = 0; g < 4; ++g) {
                const float* W = (g==0)?c0w1:(g==1)?c0w2:(g==2)?c0wa:c0wb;
                #pragma unroll
                for (int j = 0; j < 35; ++j) wcA[g][j] = W[l*48 + 13 + j];
            }
        } else if (l < 58) {
            const int r = l - 35;
            #pragma unroll
            for (int g = 0; g < 4; ++g) {
                const float* W = (g==0)?c1w1:(g==1)?c1w2:(g==2)?c1wa:c1wb;
                #pragma unroll
                for (int j = 0; j < 35; ++j) wcA[g][j] = W[r*58 + j];
            }
        } else {
            const int r = l - 58;
            #pragma unroll
            for (int g = 0; g < 4; ++g) {
                const float* W = (g==0)?c2w1:(g==1)?c2w2:(g==2)?c2wa:c2wb;
                #pragma unroll
                for (int j = 0; j < 23; ++j) wcA[g][j] = W[r*29 + j];
            }
        }
        float creg = 0.f;

        #pragma unroll 1
        for (int ts = 0; ts < TSTEPS; ++ts) {
            const int par = ts & 1, nxt = par ^ 1;
            // ---- S1: LSTM ----
            { while (flg[F_P0] < ts || flg[F_P1] < ts || flg[F_P2] < ts) {} }
            __builtin_amdgcn_sched_barrier(0);
            {
                float4 P  = *(const float4*)(smem + FLG_PS1 + par*256 + 4*l);
                float4 oa = *(const float4*)(smem + OFF_O2 + par*8);
                float2 ob = *(const float2*)(smem + OFF_O2 + par*8 + 4);
                float o2v[6] = {oa.x, oa.y, oa.z, oa.w, ob.x, ob.y};
                float a0 = P.x, a1 = P.y, a2 = P.z, a3 = P.w;
                #pragma unroll
                for (int j = 0; j < 6; ++j) {
                    a0 += o2v[j]*wlA[0][j]; a1 += o2v[j]*wlA[1][j];
                    a2 += o2v[j]*wlA[2][j]; a3 += o2v[j]*wlA[3][j];
                }
                float cn = creg * fsig(a2 + 1.f) + ftanh(a0) * fsig(a1);
                creg = cn;
                float hv = ftanh(cn) * fsig(a3);
                smem[OFF_HB + par*64 + l] = hv;
            }
            PUBLISH(F_H, ts);
            // ---- S2: CfC0 (h0 dot) ----
            STAGE36(oS2, OFF_HB + par*64, FLG_PS2 + par*256);
            if (l < 35) smem[OFF_O0 + par*36 + l] = oS2;
            PUBLISH(F_O0, ts);
            // ---- S3: CfC1 (o0 dot) ----
            POLL(F_A1, ts);
            STAGE36(oS3, OFF_O0 + par*36, FLG_PS3 + par*256);
            if (l >= 35 && l < 58) smem[OFF_O1 + par*36 + (l - 35)] = oS3;
            PUBLISH(F_O1, ts);
            // ---- S4: CfC2 (o1 dot) ----
            POLL(F_A2, ts);
            STAGE36(oS4, OFF_O1 + par*36, FLG_PS4 + par*256);
            if (l >= 58) smem[OFF_O2 + nxt*8 + (l - 58)] = oS4;
            PUBLISH(F_O2, ts);
        }
    } else if (w == 1) {
        // ============ W1: LSTM partials u0-15 + CfC1 h1-partials ============
        const int u = l >> 2, g = l & 3;              // LSTM pair p = l
        float wbx[13], wbo0[36], wbo1[24];
        #pragma unroll
        for (int j = 0; j < 13; ++j) wbx[j] = lstm_wi[(g*64 + u)*13 + j];
        #pragma unroll
        for (int j = 0; j < 36; ++j) wbo0[j] = (j < 35) ? lstm_wh[(g*64 + u)*64 + j] : 0.f;
        #pragma unroll
        for (int j = 0; j < 24; ++j) wbo1[j] = (j < 23) ? lstm_wh[(g*64 + u)*64 + 35 + j] : 0.f;
        const float bb = lstm_b[g*64 + u];
        // T_A: CfC1 h1-partials, pairs p0=l, p1=l+64 (p<92)
        const int r0 = l >> 2, g0 = l & 3;
        const int p1v = (l < 28);
        const int r1 = (l + 64) >> 2, g1 = l & 3;
        float wA0[28], wA1[28];
        {
            const float* W0 = (g0==0)?c1w1:(g0==1)?c1w2:(g0==2)?c1wa:c1wb;
            #pragma unroll
            for (int j = 0; j < 28; ++j)
                wA0[j] = (j >= 3 && j < 26) ? W0[r0*58 + 32 + j] : 0.f;
            const float* W1 = (g1==0)?c1w1:(g1==1)?c1w2:(g1==2)?c1wa:c1wb;
            #pragma unroll
            for (int j = 0; j < 28; ++j)
                wA1[j] = (p1v && j >= 3 && j < 26) ? W1[r1*58 + 32 + j] : 0.f;
        }
        const float ba0 = ((g0==0)?c1b1:(g0==1)?c1b2:(g0==2)?c1ba:c1bb)[r0];
        const float ba1 = p1v ? ((g1==0)?c1b1:(g1==1)?c1b2:(g1==2)?c1ba:c1bb)[r1] : 0.f;

        #pragma unroll 1
        for (int ts = 0; ts < TSTEPS; ++ts) {
            const int par = ts & 1, prv = par ^ 1;
            POLL(F_O0, ts - 1);
            const float* xr = smem + (((ts >> 6) & 1) ? OFF_XT1 : OFF_XT0) + (ts & 63)*13;
            float a = bb;
            #pragma unroll
            for (int j = 0; j < 13; ++j) a += xr[j] * wbx[j];
            {
                const float4* q = (const float4*)(smem + OFF_O0 + prv*36);
                float4 v0=q[0],v1=q[1],v2=q[2],v3=q[3],v4=q[4],v5=q[5],v6=q[6],v7=q[7],v8=q[8];
                float ov[36] = {v0.x,v0.y,v0.z,v0.w,v1.x,v1.y,v1.z,v1.w,
                                v2.x,v2.y,v2.z,v2.w,v3.x,v3.y,v3.z,v3.w,
                                v4.x,v4.y,v4.z,v4.w,v5.x,v5.y,v5.z,v5.w,
                                v6.x,v6.y,v6.z,v6.w,v7.x,v7.y,v7.z,v7.w,
                                v8.x,v8.y,v8.z,v8.w};
                #pragma unroll
                for (int j = 0; j < 36; ++j) a += ov[j] * wbo0[j];
            }
            POLL(F_O1, ts - 1);
            {
                const float4* q = (const float4*)(smem + OFF_O1 + prv*36);
                float4 v0=q[0],v1=q[1],v2=q[2],v3=q[3],v4=q[4],v5=q[5];
                float ov[24] = {v0.x,v0.y,v0.z,v0.w,v1.x,v1.y,v1.z,v1.w,
                                v2.x,v2.y,v2.z,v2.w,v3.x,v3.y,v3.z,v3.w,
                                v4.x,v4.y,v4.z,v4.w,v5.x,v5.y,v5.z,v5.w};
                #pragma unroll
                for (int j = 0; j < 24; ++j) a += ov[j] * wbo1[j];
            }
            smem[FLG_PS1 + par*256 + l] = a;          // index u*4+g == l
            PUBLISH(F_P0, ts);
            POLL(F_H, ts);
            {
                const float4* q = (const float4*)(smem + OFF_HB + par*64 + 32);
                float4 v0=q[0],v1=q[1],v2=q[2],v3=q[3],v4=q[4],v5=q[5],v6=q[6];
                float hv[28] = {v0.x,v0.y,v0.z,v0.w,v1.x,v1.y,v1.z,v1.w,
                                v2.x,v2.y,v2.z,v2.w,v3.x,v3.y,v3.z,v3.w,
                                v4.x,v4.y,v4.z,v4.w,v5.x,v5.y,v5.z,v5.w,
                                v6.x,v6.y,v6.z,v6.w};
                float A0 = ba0, A1 = ba1;
                #pragma unroll
                for (int j = 0; j < 28; ++j) { A0 += hv[j]*wA0[j]; A1 += hv[j]*wA1[j]; }
                smem[FLG_PS3 + par*256 + 140 + l] = A0;           // (35+r0)*4+g0
                if (p1v) smem[FLG_PS3 + par*256 + 140 + 64 + l] = A1;
            }
            PUBLISH(F_A1, ts);
        }
    } else if (w == 2) {
        // ==== W2: LSTM u16-31 + CfC0 x-partials + CfC2 h2-partials + out ====
        const int u = 16 + (l >> 2), g = l & 3;       // LSTM pair p = 64+l
        float wbx[13], wbo0[36], wbo1[24];
        #pragma unroll
        for (int j = 0; j < 13; ++j) wbx[j] = lstm_wi[(g*64 + u)*13 + j];
        #pragma unroll
        for (int j = 0; j < 36; ++j) wbo0[j] = (j < 35) ? lstm_wh[(g*64 + u)*64 + j] : 0.f;
        #pragma unroll
        for (int j = 0; j < 24; ++j) wbo1[j] = (j < 23) ? lstm_wh[(g*64 + u)*64 + 35 + j] : 0.f;
        const float bb = lstm_b[g*64 + u];
        // T_C: CfC0 x-partials, pairs p = l, 64+l, 128+l(<140)
        float wX0[13], wX1[13], wX2[13];
        float bx0, bx1, bx2;
        {
            const int r = l >> 2, gg = l & 3;
            const float* W = (gg==0)?c0w1:(gg==1)?c0w2:(gg==2)?c0wa:c0wb;
            #pragma unroll
            for (int j = 0; j < 13; ++j) wX0[j] = W[r*48 + j];
            bx0 = ((gg==0)?c0b1:(gg==1)?c0b2:(gg==2)?c0ba:c0bb)[r];
        }
        {
            const int r = (64 + l) >> 2, gg = l & 3;
            const float* W = (gg==0)?c0w1:(gg==1)?c0w2:(gg==2)?c0wa:c0wb;
            #pragma unroll
            for (int j = 0; j < 13; ++j) wX1[j] = W[r*48 + j];
            bx1 = ((gg==0)?c0b1:(gg==1)?c0b2:(gg==2)?c0ba:c0bb)[r];
        }
        {
            const int ok = (l < 12);
            const int r = ok ? ((128 + l) >> 2) : 0, gg = l & 3;
            const float* W = (gg==0)?c0w1:(gg==1)?c0w2:(gg==2)?c0wa:c0wb;
            #pragma unroll
            for (int j = 0; j < 13; ++j) wX2[j] = ok ? W[r*48 + j] : 0.f;
            bx2 = ok ? ((gg==0)?c0b1:(gg==1)?c0b2:(gg==2)?c0ba:c0bb)[r] : 0.f;
        }
        // T_A-c2: CfC2 h2-partials, lanes l<24: pair p=l
        float wC[8]; float bc2 = 0.f;
        {
            const int ok = (l < 24);
            const int r = ok ? (l >> 2) : 0, gg = l & 3;
            const float* W = (gg==0)?c2w1:(gg==1)?c2w2:(gg==2)?c2wa:c2wb;
            #pragma unroll
            for (int j = 0; j < 8; ++j)
                wC[j] = (ok && j >= 2) ? W[r*29 + 21 + j] : 0.f;
            bc2 = ok ? ((gg==0)?c2b1:(gg==1)?c2b2:(gg==2)?c2ba:c2bb)[r] : 0.f;
        }

        #pragma unroll 1
        for (int ts = 0; ts < TSTEPS; ++ts) {
            const int par = ts & 1, prv = par ^ 1;
            POLL(F_O0, ts - 1);
            const float* xr = smem + (((ts >> 6) & 1) ? OFF_XT1 : OFF_XT0) + (ts & 63)*13;
            float xv[13];
            #pragma unroll
            for (int j = 0; j < 13; ++j) xv[j] = xr[j];
            // T_C -> PS2[par]
            float cx0 = bx0, cx1 = bx1, cx2 = bx2;
            #pragma unroll
            for (int j = 0; j < 13; ++j) {
                cx0 += xv[j]*wX0[j]; cx1 += xv[j]*wX1[j]; cx2 += xv[j]*wX2[j];
            }
            smem[FLG_PS2 + par*256 + l] = cx0;
            smem[FLG_PS2 + par*256 + 64 + l] = cx1;
            if (l < 12) smem[FLG_PS2 + par*256 + 128 + l] = cx2;
            // T_B1
            float a = bb;
            #pragma unroll
            for (int j = 0; j < 13; ++j) a += xv[j] * wbx[j];
            {
                const float4* q = (const float4*)(smem + OFF_O0 + prv*36);
                float4 v0=q[0],v1=q[1],v2=q[2],v3=q[3],v4=q[4],v5=q[5],v6=q[6],v7=q[7],v8=q[8];
                float ov[36] = {v0.x,v0.y,v0.z,v0.w,v1.x,v1.y,v1.z,v1.w,
                                v2.x,v2.y,v2.z,v2.w,v3.x,v3.y,v3.z,v3.w,
                                v4.x,v4.y,v4.z,v4.w,v5.x,v5.y,v5.z,v5.w,
                                v6.x,v6.y,v6.z,v6.w,v7.x,v7.y,v7.z,v7.w,
                                v8.x,v8.y,v8.z,v8.w};
                #pragma unroll
                for (int j = 0; j < 36; ++j) a += ov[j] * wbo0[j];
            }
            POLL(F_O1, ts - 1);
            {
                const float4* q = (const float4*)(smem + OFF_O1 + prv*36);
                float4 v0=q[0],v1=q[1],v2=q[2],v3=q[3],v4=q[4],v5=q[5];
                float ov[24] = {v0.x,v0.y,v0.z,v0.w,v1.x,v1.y,v1.z,v1.w,
                                v2.x,v2.y,v2.z,v2.w,v3.x,v3.y,v3.z,v3.w,
                                v4.x,v4.y,v4.z,v4.w,v5.x,v5.y,v5.z,v5.w};
                #pragma unroll
                for (int j = 0; j < 24; ++j) a += ov[j] * wbo1[j];
            }
            smem[FLG_PS1 + par*256 + 64 + l] = a;
            PUBLISH(F_P1, ts);
            POLL(F_H, ts);
            if (l < 24) {
                const float2* q = (const float2*)(smem + OFF_HB + par*64 + 56);
                float2 h0 = q[0], h1 = q[1], h2 = q[2], h3 = q[3];
                float hv[8] = {h0.x,h0.y,h1.x,h1.y,h2.x,h2.y,h3.x,h3.y};
                float A = bc2;
                #pragma unroll
                for (int j = 0; j < 8; ++j) A += hv[j]*wC[j];
                smem[FLG_PS4 + par*256 + 232 + l] = A;            // (58+r)*4+g
            }
            PUBLISH(F_A2, ts);
            // out-tile copy (row ts-1) + flush every 64 rows
            if (ts > 0) {
                POLL(F_O2, ts - 1);
                const int rp = ts - 1, tp = (rp >> 6) & 1;
                if (l < 6)
                    smem[(tp ? OFF_OT1 : OFF_OT0) + (rp & 63)*6 + l] =
                        smem[OFF_O2 + (ts & 1)*8 + l];
                if ((ts & 63) == 0) {
                    FENCE();
                    const float* otb = smem + (tp ? OFF_OT1 : OFF_OT0);
                    float4 v = ((const float4*)otb)[l];
                    *(float4*)(out + obase + (long)(ts - 64)*6 + 4*l) = v;
                    if (l < 32) {
                        float4 v2 = ((const float4*)otb)[64 + l];
                        *(float4*)(out + obase + (long)(ts - 64)*6 + 256 + 4*l) = v2;
                    }
                }
            }
        }
        // final row + final tile
        POLL(F_O2, TSTEPS - 1);
        if (l < 6)
            smem[OFF_OT1 + 63*6 + l] = smem[OFF_O2 + 0*8 + l];   // row 4095, slot (4096&1)=0
        FENCE();
        {
            const float* otb = smem + OFF_OT1;
            float4 v = ((const float4*)otb)[l];
            *(float4*)(out + obase + (long)(TSTEPS - 64)*6 + 4*l) = v;
            if (l < 32) {
                float4 v2 = ((const float4*)otb)[64 + l];
                *(float4*)(out + obase + (long)(TSTEPS - 64)*6 + 256 + 4*l) = v2;
            }
        }
    } else {
        // ============ W3: LSTM partials u32-63 (2 pairs) + x refill ============
        const int g = l & 3;
        const int u0 = 32 + (l >> 2), u1 = 48 + (l >> 2);   // pairs 128+l, 192+l
        float wbx0[13], wbo00[36], wbo10[24];
        float wbx1[13], wbo01[36], wbo11[24];
        #pragma unroll
        for (int j = 0; j < 13; ++j) {
            wbx0[j] = lstm_wi[(g*64 + u0)*13 + j];
            wbx1[j] = lstm_wi[(g*64 + u1)*13 + j];
        }
        #pragma unroll
        for (int j = 0; j < 36; ++j) {
            wbo00[j] = (j < 35) ? lstm_wh[(g*64 + u0)*64 + j] : 0.f;
            wbo01[j] = (j < 35) ? lstm_wh[(g*64 + u1)*64 + j] : 0.f;
        }
        #pragma unroll
        for (int j = 0; j < 24; ++j) {
            wbo10[j] = (j < 23) ? lstm_wh[(g*64 + u0)*64 + 35 + j] : 0.f;
            wbo11[j] = (j < 23) ? lstm_wh[(g*64 + u1)*64 + 35 + j] : 0.f;
        }
        const float bb0 = lstm_b[g*64 + u0];
        const float bb1 = lstm_b[g*64 + u1];

        #pragma unroll 1
        for (int ts = 0; ts < TSTEPS; ++ts) {
            const int par = ts & 1, prv = par ^ 1;
            // refill: issue global loads early, LDS-write late
            float4 r0, r1, r2, r3;
            const bool doref = ((ts & 63) == 62) && (ts + 2) < TSTEPS;
            if (doref) {
                const float* src = x + xbase + (long)(ts + 2)*13;
                if (4*l + 0 < 208) r0 = *(const float4*)(src + 4*(4*l + 0));
                if (4*l + 1 < 208) r1 = *(const float4*)(src + 4*(4*l + 1));
                if (4*l + 2 < 208) r2 = *(const float4*)(src + 4*(4*l + 2));
                if (4*l + 3 < 208) r3 = *(const float4*)(src + 4*(4*l + 3));
            }
            POLL(F_O0, ts - 1);
            const float* xr = smem + (((ts >> 6) & 1) ? OFF_XT1 : OFF_XT0) + (ts & 63)*13;
            float xv[13];
            #pragma unroll
            for (int j = 0; j < 13; ++j) xv[j] = xr[j];
            float a = bb0, b = bb1;
            #pragma unroll
            for (int j = 0; j < 13; ++j) { a += xv[j]*wbx0[j]; b += xv[j]*wbx1[j]; }
            {
                const float4* q = (const float4*)(smem + OFF_O0 + prv*36);
                float4 v0=q[0],v1=q[1],v2=q[2],v3=q[3],v4=q[4],v5=q[5],v6=q[6],v7=q[7],v8=q[8];
                float ov[36] = {v0.x,v0.y,v0.z,v0.w,v1.x,v1.y,v1.z,v1.w,
                                v2.x,v2.y,v2.z,v2.w,v3.x,v3.y,v3.z,v3.w,
                                v4.x,v4.y,v4.z,v4.w,v5.x,v5.y,v5.z,v5.w,
                                v6.x,v6.y,v6.z,v6.w,v7.x,v7.y,v7.z,v7.w,
                                v8.x,v8.y,v8.z,v8.w};
                #pragma unroll
                for (int j = 0; j < 36; ++j) { a += ov[j]*wbo00[j]; b += ov[j]*wbo01[j]; }
            }
            POLL(F_O1, ts - 1);
            {
                const float4* q = (const float4*)(smem + OFF_O1 + prv*36);
                float4 v0=q[0],v1=q[1],v2=q[2],v3=q[3],v4=q[4],v5=q[5];
                float ov[24] = {v0.x,v0.y,v0.z,v0.w,v1.x,v1.y,v1.z,v1.w,
                                v2.x,v2.y,v2.z,v2.w,v3.x,v3.y,v3.z,v3.w,
                                v4.x,v4.y,v4.z,v4.w,v5.x,v5.y,v5.z,v5.w};
                #pragma unroll
                for (int j = 0; j < 24; ++j) { a += ov[j]*wbo10[j]; b += ov[j]*wbo11[j]; }
            }
            smem[FLG_PS1 + par*256 + 128 + l] = a;
            smem[FLG_PS1 + par*256 + 192 + l] = b;
            if (doref) {
                float* dst = smem + (((ts >> 6) & 1) ? OFF_XT0 : OFF_XT1);
                if (4*l + 0 < 208) *(float4*)(dst + 4*(4*l + 0)) = r0;
                if (4*l + 1 < 208) *(float4*)(dst + 4*(4*l + 1)) = r1;
                if (4*l + 2 < 208) *(float4*)(dst + 4*(4*l + 2)) = r2;
                if (4*l + 3 < 208) *(float4*)(dst + 4*(4*l + 3)) = r3;
            }
            PUBLISH(F_P2, ts);
        }
    }
}

// ---- head: rewrite pred in place, write unc ----
#define S_GW1 0
#define S_GB1 192
#define S_GW2 224
#define S_GB2 320
#define S_AW1 323
#define S_AB1 515
#define S_AW2 547
#define S_AB2 643
#define S_UW1 646
#define S_UB1 742
#define S_UW2 758
#define S_UB2 854
#define S_TOT 860

__global__ __launch_bounds__(256)
void head_kernel(const float* __restrict__ gw1, const float* __restrict__ gb1,
                 const float* __restrict__ gw2, const float* __restrict__ gb2,
                 const float* __restrict__ aw1, const float* __restrict__ ab1,
                 const float* __restrict__ aw2, const float* __restrict__ ab2,
                 const float* __restrict__ uw1, const float* __restrict__ ub1,
                 const float* __restrict__ uw2, const float* __restrict__ ub2,
                 float* __restrict__ out)
{
    __shared__ float s[S_TOT];
    const int t = threadIdx.x;
    if (t < 192) { s[S_GW1 + t] = gw1[t]; s[S_AW1 + t] = aw1[t]; }
    if (t < 96)  { s[S_GW2 + t] = gw2[t]; s[S_AW2 + t] = aw2[t];
                   s[S_UW1 + t] = uw1[t]; s[S_UW2 + t] = uw2[t]; }
    if (t < 32)  { s[S_GB1 + t] = gb1[t]; s[S_AB1 + t] = ab1[t]; }
    if (t < 16)  { s[S_UB1 + t] = ub1[t]; }
    if (t < 3)   { s[S_GB2 + t] = gb2[t]; s[S_AB2 + t] = ab2[t]; }
    if (t < 6)   { s[S_UB2 + t] = ub2[t]; }
    __syncthreads();

    const long p = (long)blockIdx.x * 256 + t;   // < B*T exactly
    const long base = p * 6;
    float m0 = out[base+0], m1 = out[base+1], m2 = out[base+2];
    float m3 = out[base+3], m4 = out[base+4], m5 = out[base+5];

    float gy0 = s[S_GB2+0], gy1 = s[S_GB2+1], gy2 = s[S_GB2+2];
    float ac0 = s[S_AB2+0], ac1 = s[S_AB2+1], ac2 = s[S_AB2+2];
    #pragma unroll
    for (int i = 0; i < 32; ++i) {
        float hg = s[S_GB1+i] + s[S_GW1+i*6+0]*m0 + s[S_GW1+i*6+1]*m1
                 + s[S_GW1+i*6+2]*m2 + s[S_GW1+i*6+3]*m3
                 + s[S_GW1+i*6+4]*m4 + s[S_GW1+i*6+5]*m5;
        hg = ftanh(hg);
        gy0 += s[S_GW2+i]*hg; gy1 += s[S_GW2+32+i]*hg; gy2 += s[S_GW2+64+i]*hg;
        float ha = s[S_AB1+i] + s[S_AW1+i*6+0]*m0 + s[S_AW1+i*6+1]*m1
                 + s[S_AW1+i*6+2]*m2 + s[S_AW1+i*6+3]*m3
                 + s[S_AW1+i*6+4]*m4 + s[S_AW1+i*6+5]*m5;
        ha = ftanh(ha);
        ac0 += s[S_AW2+i]*ha; ac1 += s[S_AW2+32+i]*ha; ac2 += s[S_AW2+64+i]*ha;
    }
    float u0 = s[S_UB2+0], u1 = s[S_UB2+1], u2 = s[S_UB2+2];
    float u3 = s[S_UB2+3], u4 = s[S_UB2+4], u5 = s[S_UB2+5];
    #pragma unroll
    for (int i = 0; i < 16; ++i) {
        float hu = s[S_UB1+i] + s[S_UW1+i*6+0]*m0 + s[S_UW1+i*6+1]*m1
                 + s[S_UW1+i*6+2]*m2 + s[S_UW1+i*6+3]*m3
                 + s[S_UW1+i*6+4]*m4 + s[S_UW1+i*6+5]*m5;
        hu = fmaxf(hu, 0.f);
        u0 += s[S_UW2+i]*hu;      u1 += s[S_UW2+16+i]*hu; u2 += s[S_UW2+32+i]*hu;
        u3 += s[S_UW2+48+i]*hu;   u4 += s[S_UW2+64+i]*hu; u5 += s[S_UW2+80+i]*hu;
    }
    out[base+0] = gy0; out[base+1] = gy1; out[base+2] = gy2;
    out[base+3] = ac0; out[base+4] = ac1; out[base+5] = ac2;
    const long uoff = (long)BATCH * TSTEPS * 6;
    out[uoff+base+0] = fsoftplus(u0); out[uoff+base+1] = fsoftplus(u1);
    out[uoff+base+2] = fsoftplus(u2); out[uoff+base+3] = fsoftplus(u3);
    out[uoff+base+4] = fsoftplus(u4); out[uoff+base+5] = fsoftplus(u5);
}

extern "C" void kernel_launch(void* const* d_in, const int* in_sizes, int n_in,
                              void* d_out, int out_size, void* d_ws, size_t ws_size,
                              hipStream_t stream) {
    const float* x       = (const float*)d_in[0];
    const float* lstm_wi = (const float*)d_in[1];
    const float* lstm_wh = (const float*)d_in[2];
    const float* lstm_b  = (const float*)d_in[3];
    const float* c0w1 = (const float*)d_in[4];
    const float* c0w2 = (const float*)d_in[5];
    const float* c0wa = (const float*)d_in[6];
    const float* c0wb = (const float*)d_in[7];
    const float* c0b1 = (const float*)d_in[8];
    const float* c0b2 = (const float*)d_in[9];
    const float* c0ba = (const float*)d_in[10];
    const float* c0bb = (const float*)d_in[11];
    const float* c1w1 = (const float*)d_in[12];
    const float* c1w2 = (const float*)d_in[13];
    const float* c1wa = (const float*)d_in[14];
    const float* c1wb = (const float*)d_in[15];
    const float* c1b1 = (const float*)d_in[16];
    const float* c1b2 = (const float*)d_in[17];
    const float* c1ba = (const float*)d_in[18];
    const float* c1bb = (const float*)d_in[19];
    const float* c2w1 = (const float*)d_in[20];
    const float* c2w2 = (const float*)d_in[21];
    const float* c2wa = (const float*)d_in[22];
    const float* c2wb = (const float*)d_in[23];
    const float* c2b1 = (const float*)d_in[24];
    const float* c2b2 = (const float*)d_in[25];
    const float* c2ba = (const float*)d_in[26];
    const float* c2bb = (const float*)d_in[27];
    const float* gw1 = (const float*)d_in[28];
    const float* gb1 = (const float*)d_in[29];
    const float* gw2 = (const float*)d_in[30];
    const float* gb2 = (const float*)d_in[31];
    const float* aw1 = (const float*)d_in[32];
    const float* ab1 = (const float*)d_in[33];
    const float* aw2 = (const float*)d_in[34];
    const float* ab2 = (const float*)d_in[35];
    const float* uw1 = (const float*)d_in[36];
    const float* ub1 = (const float*)d_in[37];
    const float* uw2 = (const float*)d_in[38];
    const float* ub2 = (const float*)d_in[39];
    float* out = (float*)d_out;

    rnn_kernel<<<BATCH, 256, 0, stream>>>(x, lstm_wi, lstm_wh, lstm_b,
        c0w1, c0w2, c0wa, c0wb, c0b1, c0b2, c0ba, c0bb,
        c1w1, c1w2, c1wa, c1wb, c1b1, c1b2, c1ba, c1bb,
        c2w1, c2w2, c2wa, c2wb, c2b1, c2b2, c2ba, c2bb, out);

    head_kernel<<<(BATCH * TSTEPS) / 256, 256, 0, stream>>>(
        gw1, gb1, gw2, gb2, aw1, ab1, aw2, ab2, uw1, ub1, uw2, ub2, out);
}